// Round 9
// baseline (1752.140 us; speedup 1.0000x reference)
//
#include <hip/hip_runtime.h>
#include <hip/hip_bf16.h>
#include <math.h>

// ---------------- problem constants ----------------
#define D        256
#define NINNER   2048
#define NROW     2049          // 2048 + dustbin
#define SP       2064          // padded row stride (floats), 16B-aligned rows
#define ITERS_N  100
#define EPS_F    0.8f
#define TAU_F    1.02f
#define NB       256           // persistent blocks
#define NT       256           // threads per block

typedef unsigned long long u64;

// exchange: u64 slots = (tag<<32)|float_bits, double-buffered by tag parity
#define PSTRIDE  2112u         // u64s per buffer (2048 rows + dustbin slot 2048 + pad)

// ws layout (in floats)
#define SZ_MAT   (2049u * 2064u)          // 4229136
#define OFF_E    0u
#define OFF_F    SZ_MAT
#define OFF_WUP  (2u * SZ_MAT)                  // u64[2][PSTRIDE] = 4*PSTRIDE floats
#define OFF_WVP  (OFF_WUP + 4u * PSTRIDE)
#define OFF_MAX0 (OFF_WVP + 4u * PSTRIDE)
#define OFF_IDX0 (OFF_MAX0 + 2048u)
#define OFF_IDX1 (OFF_IDX0 + 2048u)
#define OFF_MS0  (OFF_IDX1 + 2048u)
#define OFF_VLD0 (OFF_MS0 + 2048u)

// d_out layout (floats)
#define OOFF_Z   0u
#define OOFF_I0  (2049u * 2049u)          // 4198401
#define OOFF_I1  (OOFF_I0 + 2048u)
#define OOFF_S0  (OOFF_I1 + 2048u)
#define OOFF_S1  (OOFF_S0 + 2048u)

__device__ __forceinline__ float    pair_val(u64 x) { return __uint_as_float((unsigned)x); }
__device__ __forceinline__ unsigned pair_tag(u64 x) { return (unsigned)(x >> 32); }
__device__ __forceinline__ u64 make_pair(float v, unsigned t) {
    return ((u64)t << 32) | (u64)__float_as_uint(v);
}

// ---------------- K1: fp32 GEMM -> E = exp(scores), F = E^T (fused) ----------------
__global__ __launch_bounds__(256) void k_gemm(const float* __restrict__ A,
                                              const float* __restrict__ Bm,
                                              float* __restrict__ E,
                                              float* __restrict__ F) {
    __shared__ float As[8][64];
    __shared__ float Bs[8][64];
    const int tid = threadIdx.x;
    const int tx = tid & 15, ty = tid >> 4;
    const int row0 = blockIdx.y * 64, col0 = blockIdx.x * 64;
    float acc[4][4] = {};
    const int lr = tid >> 6, lc = tid & 63;
    for (int k0 = 0; k0 < D; k0 += 8) {
        As[lr][lc]     = A[(k0 + lr) * NINNER + row0 + lc];
        As[lr + 4][lc] = A[(k0 + lr + 4) * NINNER + row0 + lc];
        Bs[lr][lc]     = Bm[(k0 + lr) * NINNER + col0 + lc];
        Bs[lr + 4][lc] = Bm[(k0 + lr + 4) * NINNER + col0 + lc];
        __syncthreads();
#pragma unroll
        for (int kk = 0; kk < 8; ++kk) {
            const float4 av = *(const float4*)&As[kk][ty * 4];
            const float4 bv = *(const float4*)&Bs[kk][tx * 4];
            const float a_[4] = {av.x, av.y, av.z, av.w};
            const float b_[4] = {bv.x, bv.y, bv.z, bv.w};
#pragma unroll
            for (int r = 0; r < 4; ++r)
#pragma unroll
                for (int c = 0; c < 4; ++c)
                    acc[r][c] = fmaf(a_[r], b_[c], acc[r][c]);
        }
        __syncthreads();
    }
    float o[4][4];
#pragma unroll
    for (int r = 0; r < 4; ++r)
#pragma unroll
        for (int c = 0; c < 4; ++c)
            o[r][c] = expf(acc[r][c] * 0.0625f);
    const int row = row0 + ty * 4, col = col0 + tx * 4;
#pragma unroll
    for (int r = 0; r < 4; ++r)     // E tile
        *(float4*)(E + (size_t)(row + r) * SP + col)
            = make_float4(o[r][0], o[r][1], o[r][2], o[r][3]);
#pragma unroll
    for (int c = 0; c < 4; ++c)     // F tile (transposed)
        *(float4*)(F + (size_t)(col + c) * SP + row)
            = make_float4(o[0][c], o[1][c], o[2][c], o[3][c]);
}

// ---------------- K2: bins + wv pair init (tag 0) ----------------
// Only wv parity-0 needs real init; every other slot ever polled carries a
// 32-bit tag that 0xAA poison (0xAAAAAAAA) can never satisfy.
__global__ __launch_bounds__(256) void k_init(float* __restrict__ E,
                                              float* __restrict__ F,
                                              u64* __restrict__ wvb0,
                                              const float* __restrict__ alpha) {
    const int t = blockIdx.x * 256 + threadIdx.x;
    const float ea = expf(alpha[0]);
    if (t < NINNER) {
        E[(size_t)t * SP + NINNER] = ea;        // E bin column (epilogue only)
        F[(size_t)t * SP + NINNER] = ea;        // F bin column
        wvb0[t] = make_pair(1.0f, 0u);          // v0 = 0 -> wv = 1, tag 0
    }
    if (t <= NINNER) {
        E[(size_t)NINNER * SP + t] = ea;        // E bin row (+corner)
        F[(size_t)NINNER * SP + t] = ea;        // F bin row (+corner)
    }
}

// ---------------- K3: persistent Sinkhorn — WAVE-AUTONOMOUS dataflow ----------------
// Wave w of block b owns rows {8b+2w, 8b+2w+1} of E and the same-indexed cols
// (rows of F). Each wave polls the ENTIRE 2048-slot exchange itself (32
// slots/lane, lane-coalesced 64k+lane; all 32 loads issued up-front, chunk
// completion reloads only stale slots), so the dustbin total-sum is wave-local
// and the hot loop has NO __syncthreads and NO LDS: in-wave butterfly reduce,
// all lanes redundantly update u/exp, lanes 0-1 publish (tag,value) atoms.
// Tag parity double-buffering as before: causal chain bounds skew < 2 iters
// per parity buffer (no overwrite-before-read, no deadlock); 0xAA poison
// never matches a wanted tag (0..100).
__global__ __launch_bounds__(256, 1) void k_sinkhorn(const float* __restrict__ E,
                                                     const float* __restrict__ F,
                                                     u64* wub, u64* wvb,
                                                     const float* __restrict__ alpha) {
    const int b = blockIdx.x, tid = threadIdx.x;
    const int lane = tid & 63, wid = tid >> 6;
    const int row0 = b * 8 + 2 * wid;              // this wave's first row/col
    const float norm = -8.317766166719343f;        // -log(4096)
    const float logbin = 7.624618986159398f + norm; // log(2048) + norm
    const float ea = expf(alpha[0]);

    // register-resident fragments: eR[r][k] = E[row0+r][64k+lane]
    float eR[2][32], fR[2][32];
#pragma unroll
    for (int r = 0; r < 2; ++r) {
        const float* rowE = E + (size_t)(row0 + r) * SP + lane;
        const float* rowF = F + (size_t)(row0 + r) * SP + lane;
#pragma unroll
        for (int k = 0; k < 32; ++k) {
            eR[r][k] = rowE[64 * k];
            fR[r][k] = rowF[64 * k];
        }
    }

    float u0 = 0.0f, u1 = 0.0f, v0 = 0.0f, v1 = 0.0f;  // replicated across lanes
    float ub = 0.0f, vb = 0.0f, eub = 1.0f, evb = 1.0f; // dustbin replicas

    for (int it = 0; it < ITERS_N; ++it) {
        // ---- phase A: consume wv tag it, produce wu tag it+1 ----
        {
            const u64* src = wvb + (size_t)(it & 1) * PSTRIDE;
            u64* dst = wub + (size_t)((it + 1) & 1) * PSTRIDE;
            const unsigned want = (unsigned)it, prod = (unsigned)(it + 1);
            u64 a[32];
#pragma unroll
            for (int k = 0; k < 32; ++k)
                a[k] = __hip_atomic_load(src + 64 * k + lane, __ATOMIC_RELAXED, __HIP_MEMORY_SCOPE_AGENT);
            float p0 = 0.0f, p1 = 0.0f, ts = 0.0f;
#pragma unroll
            for (int c = 0; c < 4; ++c) {
                for (;;) {
                    unsigned miss = 0u;
#pragma unroll
                    for (int j = 0; j < 8; ++j)
                        miss |= (pair_tag(a[8 * c + j]) != want) ? (1u << j) : 0u;
                    if (!miss) break;
                    __builtin_amdgcn_s_sleep(1);
#pragma unroll
                    for (int j = 0; j < 8; ++j)
                        if (miss & (1u << j))
                            a[8 * c + j] = __hip_atomic_load(src + 64 * (8 * c + j) + lane,
                                                             __ATOMIC_RELAXED, __HIP_MEMORY_SCOPE_AGENT);
                }
#pragma unroll
                for (int j = 0; j < 8; ++j) {
                    const float wv = pair_val(a[8 * c + j]);
                    p0 = fmaf(eR[0][8 * c + j], wv, p0);
                    p1 = fmaf(eR[1][8 * c + j], wv, p1);
                    ts += wv;
                }
            }
#pragma unroll
            for (int m = 1; m < 64; m <<= 1) {
                p0 += __shfl_xor(p0, m, 64);
                p1 += __shfl_xor(p1, m, 64);
                ts += __shfl_xor(ts, m, 64);
            }
            const float S0 = p0 + ea * evb;
            const float S1 = p1 + ea * evb;
            u0 = u0 + EPS_F * ((norm - logf(S0)) / TAU_F - u0);
            u1 = u1 + EPS_F * ((norm - logf(S1)) / TAU_F - u1);
            const float eu0 = expf(u0), eu1 = expf(u1);
            if (lane < 2)
                __hip_atomic_store(dst + row0 + lane, make_pair(lane ? eu1 : eu0, prod),
                                   __ATOMIC_RELAXED, __HIP_MEMORY_SCOPE_AGENT);
            // dustbin replica (off the publish path)
            ub = ub + EPS_F * ((logbin - logf(ea * (ts + evb))) / TAU_F - ub);
            eub = expf(ub);
        }
        // ---- phase B: consume wu tag it+1, produce wv tag it+1 ----
        {
            const u64* src = wub + (size_t)((it + 1) & 1) * PSTRIDE;
            u64* dst = wvb + (size_t)((it + 1) & 1) * PSTRIDE;
            const unsigned want = (unsigned)(it + 1), prod = (unsigned)(it + 1);
            u64 a[32];
#pragma unroll
            for (int k = 0; k < 32; ++k)
                a[k] = __hip_atomic_load(src + 64 * k + lane, __ATOMIC_RELAXED, __HIP_MEMORY_SCOPE_AGENT);
            float p0 = 0.0f, p1 = 0.0f, ts = 0.0f;
#pragma unroll
            for (int c = 0; c < 4; ++c) {
                for (;;) {
                    unsigned miss = 0u;
#pragma unroll
                    for (int j = 0; j < 8; ++j)
                        miss |= (pair_tag(a[8 * c + j]) != want) ? (1u << j) : 0u;
                    if (!miss) break;
                    __builtin_amdgcn_s_sleep(1);
#pragma unroll
                    for (int j = 0; j < 8; ++j)
                        if (miss & (1u << j))
                            a[8 * c + j] = __hip_atomic_load(src + 64 * (8 * c + j) + lane,
                                                             __ATOMIC_RELAXED, __HIP_MEMORY_SCOPE_AGENT);
                }
#pragma unroll
                for (int j = 0; j < 8; ++j) {
                    const float wu = pair_val(a[8 * c + j]);
                    p0 = fmaf(fR[0][8 * c + j], wu, p0);
                    p1 = fmaf(fR[1][8 * c + j], wu, p1);
                    ts += wu;
                }
            }
#pragma unroll
            for (int m = 1; m < 64; m <<= 1) {
                p0 += __shfl_xor(p0, m, 64);
                p1 += __shfl_xor(p1, m, 64);
                ts += __shfl_xor(ts, m, 64);
            }
            const float T0 = p0 + ea * eub;
            const float T1 = p1 + ea * eub;
            v0 = v0 + EPS_F * ((norm - logf(T0)) / TAU_F - v0);
            v1 = v1 + EPS_F * ((norm - logf(T1)) / TAU_F - v1);
            const float ev0 = expf(v0), ev1 = expf(v1);
            if (lane < 2)
                __hip_atomic_store(dst + row0 + lane, make_pair(lane ? ev1 : ev0, prod),
                                   __ATOMIC_RELAXED, __HIP_MEMORY_SCOPE_AGENT);
            vb = vb + EPS_F * ((logbin - logf(ea * (ts + eub))) / TAU_F - vb);
            evb = expf(vb);
        }
    }
    // publish final dustbin scalings (tag 100 -> parity 0) for the epilogue
    if (b == NB - 1 && tid == 0) {
        __hip_atomic_store(wub + NINNER, make_pair(eub, (unsigned)ITERS_N),
                           __ATOMIC_RELAXED, __HIP_MEMORY_SCOPE_AGENT);
        __hip_atomic_store(wvb + NINNER, make_pair(evb, (unsigned)ITERS_N),
                           __ATOMIC_RELAXED, __HIP_MEMORY_SCOPE_AGENT);
    }
}

// ---------------- K4: fused epilogue — out0 = exp(Z), row argmax, col argmax ----------
// final wu/wv: tag 100 (even) -> parity-0 buffer halves -> .x of float2 pairs
__global__ __launch_bounds__(256) void k_finish(const float* __restrict__ E,
                                                const float* __restrict__ F,
                                                const float2* __restrict__ wup,
                                                const float2* __restrict__ wvp,
                                                float* __restrict__ out,
                                                float* __restrict__ max0,
                                                int* __restrict__ idx0,
                                                int* __restrict__ idx1) {
    const int i = blockIdx.x;                 // 0..2048
    const int tid = threadIdx.x;
    const int lane = tid & 63, wid = tid >> 6;
    __shared__ float sb[4]; __shared__ int si[4];

    // --- row part: write out row i, argmax over inner cols ---
    {
        const float wui = wup[i].x * 4096.0f;     // * exp(-norm)
        const float* row = E + (size_t)i * SP;
        float best = -1.0f; int bidx = 0;
        for (int j = tid; j < NROW; j += 256) {
            const float val = row[j] * wvp[j].x * wui;
            out[(size_t)i * NROW + j] = val;
            if (j < NINNER && val > best) { best = val; bidx = j; }
        }
        if (i < NINNER) {
#pragma unroll
            for (int m = 1; m < 64; m <<= 1) {
                const float ob = __shfl_xor(best, m, 64);
                const int   oi = __shfl_xor(bidx, m, 64);
                if (ob > best || (ob == best && oi < bidx)) { best = ob; bidx = oi; }
            }
            if (lane == 0) { sb[wid] = best; si[wid] = bidx; }
            __syncthreads();
            if (tid == 0) {
                for (int k = 1; k < 4; ++k)
                    if (sb[k] > best || (sb[k] == best && si[k] < bidx)) { best = sb[k]; bidx = si[k]; }
                max0[i] = best; idx0[i] = bidx;
            }
        }
    }

    // --- col part: argmax of column i over inner rows (via F) ---
    if (i < NINNER) {
        __syncthreads();                          // sb/si reuse safety
        const float* row = F + (size_t)i * SP;
        float best = -1.0f; int bidx = 0;
        for (int r = tid; r < NINNER; r += 256) {
            const float q = row[r] * wup[r].x;
            if (q > best) { best = q; bidx = r; }
        }
#pragma unroll
        for (int m = 1; m < 64; m <<= 1) {
            const float ob = __shfl_xor(best, m, 64);
            const int   oi = __shfl_xor(bidx, m, 64);
            if (ob > best || (ob == best && oi < bidx)) { best = ob; bidx = oi; }
        }
        if (lane == 0) { sb[wid] = best; si[wid] = bidx; }
        __syncthreads();
        if (tid == 0) {
            for (int k = 1; k < 4; ++k)
                if (sb[k] > best || (sb[k] == best && si[k] < bidx)) { best = sb[k]; bidx = si[k]; }
            idx1[i] = bidx;
        }
    }
}

// ---------------- K5a/K5b: mutual matching ----------------
__global__ __launch_bounds__(256) void k_match0(const float* __restrict__ max0,
                                                const int* __restrict__ idx0,
                                                const int* __restrict__ idx1,
                                                float* __restrict__ ms0,
                                                int* __restrict__ vld0,
                                                float* __restrict__ out) {
    const int i = blockIdx.x * 256 + threadIdx.x;
    if (i >= NINNER) return;
    const int j = idx0[i];
    const bool mut = (idx1[j] == i);
    const float ms = mut ? max0[i] : 0.0f;
    const bool val = mut && (ms > 0.2f);
    ms0[i] = ms; vld0[i] = val ? 1 : 0;
    out[OOFF_I0 + i] = val ? (float)j : -1.0f;
    out[OOFF_S0 + i] = ms;
}
__global__ __launch_bounds__(256) void k_match1(const int* __restrict__ idx0,
                                                const int* __restrict__ idx1,
                                                const float* __restrict__ ms0,
                                                const int* __restrict__ vld0,
                                                float* __restrict__ out) {
    const int j = blockIdx.x * 256 + threadIdx.x;
    if (j >= NINNER) return;
    const int i = idx1[j];
    const bool mut = (idx0[i] == j);
    const float ms = mut ? ms0[i] : 0.0f;
    const bool val = mut && (vld0[i] != 0);
    out[OOFF_I1 + j] = val ? (float)i : -1.0f;
    out[OOFF_S1 + j] = ms;
}

// ---------------- host ----------------
extern "C" void kernel_launch(void* const* d_in, const int* in_sizes, int n_in,
                              void* d_out, int out_size, void* d_ws, size_t ws_size,
                              hipStream_t stream) {
    const float* A     = (const float*)d_in[0];   // mdesc0 (1,256,2048)
    const float* Bm    = (const float*)d_in[1];   // mdesc1 (1,256,2048)
    const float* alpha = (const float*)d_in[2];   // bin_score scalar

    float* ws = (float*)d_ws;
    float* E    = ws + OFF_E;
    float* F    = ws + OFF_F;
    u64*   wub  = (u64*)(ws + OFF_WUP);
    u64*   wvb  = (u64*)(ws + OFF_WVP);
    float* max0 = ws + OFF_MAX0;
    int*   idx0 = (int*)(ws + OFF_IDX0);
    int*   idx1 = (int*)(ws + OFF_IDX1);
    float* ms0  = ws + OFF_MS0;
    int*   vld0 = (int*)(ws + OFF_VLD0);
    float* out  = (float*)d_out;

    k_gemm<<<dim3(32, 32), 256, 0, stream>>>(A, Bm, E, F);
    k_init<<<dim3(9), 256, 0, stream>>>(E, F, wvb, alpha);
    k_sinkhorn<<<dim3(NB), NT, 0, stream>>>(E, F, wub, wvb, alpha);
    // final tag 100 (even) -> parity-0 halves of both pair buffers
    k_finish<<<dim3(NROW), 256, 0, stream>>>(E, F, (const float2*)wub, (const float2*)wvb,
                                             out, max0, idx0, idx1);
    k_match0<<<dim3(8), 256, 0, stream>>>(max0, idx0, idx1, ms0, vld0, out);
    k_match1<<<dim3(8), 256, 0, stream>>>(idx0, idx1, ms0, vld0, out);
}

// Round 10
// 946.930 us; speedup vs baseline: 1.8503x; 1.8503x over previous
//
#include <hip/hip_runtime.h>
#include <hip/hip_bf16.h>
#include <math.h>

// ---------------- problem constants ----------------
#define D        256
#define NINNER   2048
#define NROW     2049          // 2048 + dustbin
#define SP       2064          // padded row stride (floats), 16B-aligned rows
#define ITERS_N  100
#define EPS_F    0.8f
#define TAU_F    1.02f
#define NB       256           // persistent blocks
#define NT       256           // threads per block

typedef unsigned long long u64;

// exchange: u64 = 2 packed fp32, freshness = sign bits (tag k -> sign (k>>1)&1,
// parity k&1 picks buffer). 1024 u64 = 2048 values per buffer.
#define PSTRIDE  1088u         // u64s per buffer half (1024 used + pad)
#define SGNMASK  0x8000000080000000ull

// ws layout (in floats)
#define SZ_MAT   (2049u * 2064u)          // 4229136
#define OFF_E    0u
#define OFF_F    SZ_MAT
#define OFF_WUP  (2u * SZ_MAT)                  // u64[2][PSTRIDE]
#define OFF_WVP  (OFF_WUP + 4u * PSTRIDE)
#define OFF_MAX0 (OFF_WVP + 4u * PSTRIDE)
#define OFF_IDX0 (OFF_MAX0 + 2048u)
#define OFF_IDX1 (OFF_IDX0 + 2048u)
#define OFF_MS0  (OFF_IDX1 + 2048u)
#define OFF_VLD0 (OFF_MS0 + 2048u)

// d_out layout (floats)
#define OOFF_Z   0u
#define OOFF_I0  (2049u * 2049u)          // 4198401
#define OOFF_I1  (OOFF_I0 + 2048u)
#define OOFF_S0  (OOFF_I1 + 2048u)
#define OOFF_S1  (OOFF_S0 + 2048u)

__device__ __forceinline__ u64 pack_pair(float lo, float hi, unsigned sbit31) {
    return ((u64)(__float_as_uint(hi) | sbit31) << 32)
         |  (u64)(__float_as_uint(lo) | sbit31);
}

// ---------------- K1: fp32 GEMM -> E = exp(scores), F = E^T (fused) ----------------
__global__ __launch_bounds__(256) void k_gemm(const float* __restrict__ A,
                                              const float* __restrict__ Bm,
                                              float* __restrict__ E,
                                              float* __restrict__ F) {
    __shared__ float As[8][64];
    __shared__ float Bs[8][64];
    const int tid = threadIdx.x;
    const int tx = tid & 15, ty = tid >> 4;
    const int row0 = blockIdx.y * 64, col0 = blockIdx.x * 64;
    float acc[4][4] = {};
    const int lr = tid >> 6, lc = tid & 63;
    for (int k0 = 0; k0 < D; k0 += 8) {
        As[lr][lc]     = A[(k0 + lr) * NINNER + row0 + lc];
        As[lr + 4][lc] = A[(k0 + lr + 4) * NINNER + row0 + lc];
        Bs[lr][lc]     = Bm[(k0 + lr) * NINNER + col0 + lc];
        Bs[lr + 4][lc] = Bm[(k0 + lr + 4) * NINNER + col0 + lc];
        __syncthreads();
#pragma unroll
        for (int kk = 0; kk < 8; ++kk) {
            const float4 av = *(const float4*)&As[kk][ty * 4];
            const float4 bv = *(const float4*)&Bs[kk][tx * 4];
            const float a_[4] = {av.x, av.y, av.z, av.w};
            const float b_[4] = {bv.x, bv.y, bv.z, bv.w};
#pragma unroll
            for (int r = 0; r < 4; ++r)
#pragma unroll
                for (int c = 0; c < 4; ++c)
                    acc[r][c] = fmaf(a_[r], b_[c], acc[r][c]);
        }
        __syncthreads();
    }
    float o[4][4];
#pragma unroll
    for (int r = 0; r < 4; ++r)
#pragma unroll
        for (int c = 0; c < 4; ++c)
            o[r][c] = expf(acc[r][c] * 0.0625f);
    const int row = row0 + ty * 4, col = col0 + tx * 4;
#pragma unroll
    for (int r = 0; r < 4; ++r)     // E tile
        *(float4*)(E + (size_t)(row + r) * SP + col)
            = make_float4(o[r][0], o[r][1], o[r][2], o[r][3]);
#pragma unroll
    for (int c = 0; c < 4; ++c)     // F tile (transposed)
        *(float4*)(F + (size_t)(col + c) * SP + row)
            = make_float4(o[0][c], o[1][c], o[2][c], o[3][c]);
}

// ---------------- K2: exchange-buffer init ----------------
// wv parity0 = real tag-0 values (+1, sign 0). Other three halves init with the
// OPPOSITE sign of their first-wanted tag so stale/poison never passes:
//   wu parity0 first want tag2 (s=1) -> init s=0 ; wu parity1 first want tag1
//   (s=0) -> init s=1 ; wv parity1 first want tag1 (s=0) -> init s=1.
__global__ __launch_bounds__(256) void k_init(u64* __restrict__ wub,
                                              u64* __restrict__ wvb) {
    const int t = blockIdx.x * 256 + threadIdx.x;
    if (t < 1024) {
        const u64 pos = pack_pair(1.0f, 1.0f, 0u);
        const u64 neg = pack_pair(1.0f, 1.0f, 0x80000000u);
        wvb[t]           = pos;                 // real wv(0) = 1.0, tag 0
        wvb[PSTRIDE + t] = neg;
        wub[t]           = pos;
        wub[PSTRIDE + t] = neg;
    }
}

// ---------------- poll 4 pair-atoms, coalesced slot = k*256+tid ----------------
__device__ __forceinline__ void poll4(const u64* __restrict__ buf, int tid,
                                      u64 expect, float* w) {
    u64 a[4];
#pragma unroll
    for (int k = 0; k < 4; ++k)
        a[k] = __hip_atomic_load(buf + 256 * k + tid, __ATOMIC_RELAXED, __HIP_MEMORY_SCOPE_AGENT);
    for (;;) {
        unsigned miss = 0u;
#pragma unroll
        for (int k = 0; k < 4; ++k)
            miss |= (((a[k] ^ expect) & SGNMASK) != 0ull) ? (1u << k) : 0u;
        if (!miss) break;
        __builtin_amdgcn_s_sleep(1);
#pragma unroll
        for (int k = 0; k < 4; ++k)
            if (miss & (1u << k))
                a[k] = __hip_atomic_load(buf + 256 * k + tid, __ATOMIC_RELAXED, __HIP_MEMORY_SCOPE_AGENT);
    }
#pragma unroll
    for (int k = 0; k < 4; ++k) {
        w[2 * k]     = fabsf(__uint_as_float((unsigned)a[k]));
        w[2 * k + 1] = fabsf(__uint_as_float((unsigned)(a[k] >> 32)));
    }
}

// argmax merge helper (prefer lower index on ties)
#define AMAX(bv, bi, ov, oi) if ((ov) > (bv) || ((ov) == (bv) && (oi) < (bi))) { (bv) = (ov); (bi) = (oi); }

// ---------------- K3: persistent Sinkhorn + fused epilogue ----------------
// Block b owns rows [8b,8b+8) of E and cols [8b,8b+8) of F. Thread tid's value
// slice: j in {512k + 2*tid + h : k<4, h<2} (matches pair slot k*256+tid).
// Thread tid<4 maintains TWO row/col potentials (rows base+2*tid, +1) and packs
// its own publish pair — no shuffles, no extra barrier on the publish path.
// Dustbin potentials locally replicated (r6). After the loop, each block writes
// its 8 out0 rows + row/col argmaxes directly from register fragments (one
// extra poll of wv tag 100) — k_finish eliminated.
__global__ __launch_bounds__(256, 1) void k_sinkhorn(const float* __restrict__ E,
                                                     const float* __restrict__ F,
                                                     u64* wub, u64* wvb,
                                                     const float* __restrict__ alpha,
                                                     float* __restrict__ out,
                                                     float* __restrict__ max0,
                                                     int* __restrict__ idx0,
                                                     int* __restrict__ idx1) {
    const int b = blockIdx.x, tid = threadIdx.x;
    const int lane = tid & 63, wid = tid >> 6;
    const int base = b * 8;
    __shared__ float red[2][4][9];

    const float norm = -8.317766166719343f;            // -log(4096)
    const float logbin = 7.624618986159398f + norm;     // log(2048) + norm
    const float ea = expf(alpha[0]);

    // fragments: eR[r][2k+h] = E[base+r][512k + 2*tid + h]
    float eR[8][8], fR[8][8];
#pragma unroll
    for (int r = 0; r < 8; ++r) {
        const float* rowE = E + (size_t)(base + r) * SP + 2 * tid;
        const float* rowF = F + (size_t)(base + r) * SP + 2 * tid;
#pragma unroll
        for (int k = 0; k < 4; ++k) {
            const float2 e = *(const float2*)(rowE + 512 * k);
            const float2 f = *(const float2*)(rowF + 512 * k);
            eR[r][2 * k] = e.x; eR[r][2 * k + 1] = e.y;
            fR[r][2 * k] = f.x; fR[r][2 * k + 1] = f.y;
        }
    }

    float uA = 0.0f, uB = 0.0f, vA = 0.0f, vB = 0.0f;   // tid<4: rows/cols base+2tid,+1
    float euA = 1.0f, euB = 1.0f;                        // latest exp(u) (tid<4)
    float ubp = 0.0f, vbp = 0.0f, eub = 1.0f, evb = 1.0f; // dustbin replicas
    float wuF[8];                                        // final wu (saved at it=99)

    for (int it = 0; it < ITERS_N; ++it) {
        // ---- phase A: consume wv tag it, produce wu tag it+1 ----
        {
            const u64* src = wvb + (size_t)(it & 1) * PSTRIDE;
            u64* dst = wub + (size_t)((it + 1) & 1) * PSTRIDE;
            const u64 expw = ((it >> 1) & 1) ? SGNMASK : 0ull;
            const unsigned sbit = (((it + 1) >> 1) & 1) << 31;
            float w[8];
            poll4(src, tid, expw, w);
            float p[8];
#pragma unroll
            for (int r = 0; r < 8; ++r) {
                float s = 0.0f;
#pragma unroll
                for (int q = 0; q < 8; ++q) s = fmaf(eR[r][q], w[q], s);
                p[r] = s;
            }
            float t = w[0] + w[1] + w[2] + w[3] + w[4] + w[5] + w[6] + w[7];
#pragma unroll
            for (int r = 0; r < 8; ++r) {
                float s = p[r];
#pragma unroll
                for (int m = 1; m < 64; m <<= 1) s += __shfl_xor(s, m, 64);
                if (lane == 0) red[0][wid][r] = s;
            }
#pragma unroll
            for (int m = 1; m < 64; m <<= 1) t += __shfl_xor(t, m, 64);
            if (lane == 0) red[0][wid][8] = t;
            __syncthreads();
            if (tid < 4) {
                const float SA = red[0][0][2 * tid]     + red[0][1][2 * tid]
                               + red[0][2][2 * tid]     + red[0][3][2 * tid]     + ea * evb;
                const float SB = red[0][0][2 * tid + 1] + red[0][1][2 * tid + 1]
                               + red[0][2][2 * tid + 1] + red[0][3][2 * tid + 1] + ea * evb;
                uA = uA + EPS_F * ((norm - logf(SA)) / TAU_F - uA);
                uB = uB + EPS_F * ((norm - logf(SB)) / TAU_F - uB);
                euA = expf(uA); euB = expf(uB);
                __hip_atomic_store(dst + 4 * b + tid, pack_pair(euA, euB, sbit),
                                   __ATOMIC_RELAXED, __HIP_MEMORY_SCOPE_AGENT);
            }
            const float tsum = red[0][0][8] + red[0][1][8] + red[0][2][8] + red[0][3][8];
            ubp = ubp + EPS_F * ((logbin - logf(ea * (tsum + evb))) / TAU_F - ubp);
            eub = expf(ubp);
        }
        // ---- phase B: consume wu tag it+1, produce wv tag it+1 ----
        {
            const u64* src = wub + (size_t)((it + 1) & 1) * PSTRIDE;
            u64* dst = wvb + (size_t)((it + 1) & 1) * PSTRIDE;
            const u64 expw = (((it + 1) >> 1) & 1) ? SGNMASK : 0ull;
            const unsigned sbit = (((it + 1) >> 1) & 1) << 31;
            float w[8];
            poll4(src, tid, expw, w);
            if (it == ITERS_N - 1) {
#pragma unroll
                for (int q = 0; q < 8; ++q) wuF[q] = w[q];
            }
            float p[8];
#pragma unroll
            for (int r = 0; r < 8; ++r) {
                float s = 0.0f;
#pragma unroll
                for (int q = 0; q < 8; ++q) s = fmaf(fR[r][q], w[q], s);
                p[r] = s;
            }
            float t = w[0] + w[1] + w[2] + w[3] + w[4] + w[5] + w[6] + w[7];
#pragma unroll
            for (int r = 0; r < 8; ++r) {
                float s = p[r];
#pragma unroll
                for (int m = 1; m < 64; m <<= 1) s += __shfl_xor(s, m, 64);
                if (lane == 0) red[1][wid][r] = s;
            }
#pragma unroll
            for (int m = 1; m < 64; m <<= 1) t += __shfl_xor(t, m, 64);
            if (lane == 0) red[1][wid][8] = t;
            __syncthreads();
            if (tid < 4) {
                const float TA = red[1][0][2 * tid]     + red[1][1][2 * tid]
                               + red[1][2][2 * tid]     + red[1][3][2 * tid]     + ea * eub;
                const float TB = red[1][0][2 * tid + 1] + red[1][1][2 * tid + 1]
                               + red[1][2][2 * tid + 1] + red[1][3][2 * tid + 1] + ea * eub;
                vA = vA + EPS_F * ((norm - logf(TA)) / TAU_F - vA);
                vB = vB + EPS_F * ((norm - logf(TB)) / TAU_F - vB);
                __hip_atomic_store(dst + 4 * b + tid, pack_pair(expf(vA), expf(vB), sbit),
                                   __ATOMIC_RELAXED, __HIP_MEMORY_SCOPE_AGENT);
            }
            const float tsum = red[1][0][8] + red[1][1][8] + red[1][2][8] + red[1][3][8];
            vbp = vbp + EPS_F * ((logbin - logf(ea * (tsum + eub))) / TAU_F - vbp);
            evb = expf(vbp);
        }
    }

    // ================= fused epilogue =================
    // final wv: tag 100 -> parity 0, sign 0. Per-location monotonicity: this
    // thread last saw tag 98 (sign 1) in these slots, so sign-0 => tag 100.
    __shared__ float feu[8];
    __shared__ float rv[4][8]; __shared__ int ri[4][8];
    if (tid < 4) { feu[2 * tid] = euA; feu[2 * tid + 1] = euB; }
    float wvF[8];
    poll4(wvb, tid, 0ull, wvF);
    __syncthreads();

    // --- rows: write out0 + row argmax ---
    float bv[8]; int bi[8];
#pragma unroll
    for (int r = 0; r < 8; ++r) {
        const float s = feu[r] * 4096.0f;
        float best = -1.0f; int besti = 0;
#pragma unroll
        for (int k = 0; k < 4; ++k) {
#pragma unroll
            for (int h = 0; h < 2; ++h) {
                const int j = 512 * k + 2 * tid + h;
                const float val = eR[r][2 * k + h] * wvF[2 * k + h] * s;
                out[(size_t)(base + r) * NROW + j] = val;
                AMAX(best, besti, val, j);
            }
        }
        bv[r] = best; bi[r] = besti;
    }
#pragma unroll
    for (int r = 0; r < 8; ++r) {
#pragma unroll
        for (int m = 1; m < 64; m <<= 1) {
            const float ov = __shfl_xor(bv[r], m, 64);
            const int   oi = __shfl_xor(bi[r], m, 64);
            AMAX(bv[r], bi[r], ov, oi);
        }
        if (lane == 0) { rv[wid][r] = bv[r]; ri[wid][r] = bi[r]; }
    }
    __syncthreads();
    if (tid < 8) {
        float best = rv[0][tid]; int besti = ri[0][tid];
        for (int k = 1; k < 4; ++k) AMAX(best, besti, rv[k][tid], ri[k][tid]);
        max0[base + tid] = best; idx0[base + tid] = besti;
        // dustbin column of this row
        out[(size_t)(base + tid) * NROW + NINNER] = ea * feu[tid] * evb * 4096.0f;
    }
    __syncthreads();        // rv/ri reuse

    // --- cols: argmax over i (via F fragments and final wu) ---
#pragma unroll
    for (int r = 0; r < 8; ++r) {
        float best = -1.0f; int besti = 0;
#pragma unroll
        for (int k = 0; k < 4; ++k) {
#pragma unroll
            for (int h = 0; h < 2; ++h) {
                const int i = 512 * k + 2 * tid + h;
                const float q = fR[r][2 * k + h] * wuF[2 * k + h];
                AMAX(best, besti, q, i);
            }
        }
        bv[r] = best; bi[r] = besti;
    }
#pragma unroll
    for (int r = 0; r < 8; ++r) {
#pragma unroll
        for (int m = 1; m < 64; m <<= 1) {
            const float ov = __shfl_xor(bv[r], m, 64);
            const int   oi = __shfl_xor(bi[r], m, 64);
            AMAX(bv[r], bi[r], ov, oi);
        }
        if (lane == 0) { rv[wid][r] = bv[r]; ri[wid][r] = bi[r]; }
    }
    __syncthreads();
    if (tid < 8) {
        float best = rv[0][tid]; int besti = ri[0][tid];
        for (int k = 1; k < 4; ++k) AMAX(best, besti, rv[k][tid], ri[k][tid]);
        idx1[base + tid] = besti;
    }

    // --- dustbin row (+ corner) by the last block ---
    if (b == NB - 1) {
        const float s = ea * eub * 4096.0f;
#pragma unroll
        for (int k = 0; k < 4; ++k)
#pragma unroll
            for (int h = 0; h < 2; ++h) {
                const int j = 512 * k + 2 * tid + h;
                out[(size_t)NINNER * NROW + j] = s * wvF[2 * k + h];
            }
        if (tid == 0)
            out[(size_t)NINNER * NROW + NINNER] = s * evb;
    }
}

// ---------------- K5a/K5b: mutual matching ----------------
__global__ __launch_bounds__(256) void k_match0(const float* __restrict__ max0,
                                                const int* __restrict__ idx0,
                                                const int* __restrict__ idx1,
                                                float* __restrict__ ms0,
                                                int* __restrict__ vld0,
                                                float* __restrict__ out) {
    const int i = blockIdx.x * 256 + threadIdx.x;
    if (i >= NINNER) return;
    const int j = idx0[i];
    const bool mut = (idx1[j] == i);
    const float ms = mut ? max0[i] : 0.0f;
    const bool val = mut && (ms > 0.2f);
    ms0[i] = ms; vld0[i] = val ? 1 : 0;
    out[OOFF_I0 + i] = val ? (float)j : -1.0f;
    out[OOFF_S0 + i] = ms;
}
__global__ __launch_bounds__(256) void k_match1(const int* __restrict__ idx0,
                                                const int* __restrict__ idx1,
                                                const float* __restrict__ ms0,
                                                const int* __restrict__ vld0,
                                                float* __restrict__ out) {
    const int j = blockIdx.x * 256 + threadIdx.x;
    if (j >= NINNER) return;
    const int i = idx1[j];
    const bool mut = (idx0[i] == j);
    const float ms = mut ? ms0[i] : 0.0f;
    const bool val = mut && (vld0[i] != 0);
    out[OOFF_I1 + j] = val ? (float)i : -1.0f;
    out[OOFF_S1 + j] = ms;
}

// ---------------- host ----------------
extern "C" void kernel_launch(void* const* d_in, const int* in_sizes, int n_in,
                              void* d_out, int out_size, void* d_ws, size_t ws_size,
                              hipStream_t stream) {
    const float* A     = (const float*)d_in[0];   // mdesc0 (1,256,2048)
    const float* Bm    = (const float*)d_in[1];   // mdesc1 (1,256,2048)
    const float* alpha = (const float*)d_in[2];   // bin_score scalar

    float* ws = (float*)d_ws;
    float* E    = ws + OFF_E;
    float* F    = ws + OFF_F;
    u64*   wub  = (u64*)(ws + OFF_WUP);
    u64*   wvb  = (u64*)(ws + OFF_WVP);
    float* max0 = ws + OFF_MAX0;
    int*   idx0 = (int*)(ws + OFF_IDX0);
    int*   idx1 = (int*)(ws + OFF_IDX1);
    float* ms0  = ws + OFF_MS0;
    int*   vld0 = (int*)(ws + OFF_VLD0);
    float* out  = (float*)d_out;

    k_gemm<<<dim3(32, 32), 256, 0, stream>>>(A, Bm, E, F);
    k_init<<<dim3(4), 256, 0, stream>>>(wub, wvb);
    k_sinkhorn<<<dim3(NB), NT, 0, stream>>>(E, F, wub, wvb, alpha,
                                            out, max0, idx0, idx1);
    k_match0<<<dim3(8), 256, 0, stream>>>(max0, idx0, idx1, ms0, vld0, out);
    k_match1<<<dim3(8), 256, 0, stream>>>(idx0, idx1, ms0, vld0, out);
}

// Round 11
// 902.668 us; speedup vs baseline: 1.9411x; 1.0490x over previous
//
#include <hip/hip_runtime.h>
#include <hip/hip_bf16.h>
#include <math.h>

// ---------------- problem constants ----------------
#define D        256
#define NINNER   2048
#define NROW     2049          // 2048 + dustbin
#define SP       2064          // padded row stride (floats), 16B-aligned rows
#define ITERS_N  100
#define EPS_F    0.8f
#define TAU_F    1.02f
#define NB       256           // persistent blocks
#define NT       256           // threads per block
#define RREP     4             // exchange replicas (spread MALL line readers)

typedef unsigned long long u64;

// exchange: u64 slots = (tag<<32)|float_bits, double-buffered by tag parity,
// REPLICATED x4: buffer[parity][rep][slot]. Consumer block b polls rep b&3.
#define PSTRIDE  2112u         // u64 slots per replica (2048 + dustbin + pad)

// ws layout (in floats)
#define SZ_MAT   (2049u * 2064u)          // 4229136
#define OFF_E    0u
#define OFF_F    SZ_MAT
#define SZ_XCHG  (2u * RREP * PSTRIDE * 2u)     // floats per exchange buffer
#define OFF_WUP  (2u * SZ_MAT)
#define OFF_WVP  (OFF_WUP + SZ_XCHG)
#define OFF_MAX0 (OFF_WVP + SZ_XCHG)
#define OFF_IDX0 (OFF_MAX0 + 2048u)
#define OFF_IDX1 (OFF_IDX0 + 2048u)
#define OFF_MS0  (OFF_IDX1 + 2048u)
#define OFF_VLD0 (OFF_MS0 + 2048u)

// d_out layout (floats)
#define OOFF_Z   0u
#define OOFF_I0  (2049u * 2049u)          // 4198401
#define OOFF_I1  (OOFF_I0 + 2048u)
#define OOFF_S0  (OOFF_I1 + 2048u)
#define OOFF_S1  (OOFF_S0 + 2048u)

__device__ __forceinline__ float    pair_val(u64 x) { return __uint_as_float((unsigned)x); }
__device__ __forceinline__ unsigned pair_tag(u64 x) { return (unsigned)(x >> 32); }
__device__ __forceinline__ u64 make_pair(float v, unsigned t) {
    return ((u64)t << 32) | (u64)__float_as_uint(v);
}

// ---------------- K1: fp32 GEMM -> E = exp(scores), F = E^T (fused) ----------------
__global__ __launch_bounds__(256) void k_gemm(const float* __restrict__ A,
                                              const float* __restrict__ Bm,
                                              float* __restrict__ E,
                                              float* __restrict__ F) {
    __shared__ float As[8][64];
    __shared__ float Bs[8][64];
    const int tid = threadIdx.x;
    const int tx = tid & 15, ty = tid >> 4;
    const int row0 = blockIdx.y * 64, col0 = blockIdx.x * 64;
    float acc[4][4] = {};
    const int lr = tid >> 6, lc = tid & 63;
    for (int k0 = 0; k0 < D; k0 += 8) {
        As[lr][lc]     = A[(k0 + lr) * NINNER + row0 + lc];
        As[lr + 4][lc] = A[(k0 + lr + 4) * NINNER + row0 + lc];
        Bs[lr][lc]     = Bm[(k0 + lr) * NINNER + col0 + lc];
        Bs[lr + 4][lc] = Bm[(k0 + lr + 4) * NINNER + col0 + lc];
        __syncthreads();
#pragma unroll
        for (int kk = 0; kk < 8; ++kk) {
            const float4 av = *(const float4*)&As[kk][ty * 4];
            const float4 bv = *(const float4*)&Bs[kk][tx * 4];
            const float a_[4] = {av.x, av.y, av.z, av.w};
            const float b_[4] = {bv.x, bv.y, bv.z, bv.w};
#pragma unroll
            for (int r = 0; r < 4; ++r)
#pragma unroll
                for (int c = 0; c < 4; ++c)
                    acc[r][c] = fmaf(a_[r], b_[c], acc[r][c]);
        }
        __syncthreads();
    }
    float o[4][4];
#pragma unroll
    for (int r = 0; r < 4; ++r)
#pragma unroll
        for (int c = 0; c < 4; ++c)
            o[r][c] = expf(acc[r][c] * 0.0625f);
    const int row = row0 + ty * 4, col = col0 + tx * 4;
#pragma unroll
    for (int r = 0; r < 4; ++r)     // E tile
        *(float4*)(E + (size_t)(row + r) * SP + col)
            = make_float4(o[r][0], o[r][1], o[r][2], o[r][3]);
#pragma unroll
    for (int c = 0; c < 4; ++c)     // F tile (transposed)
        *(float4*)(F + (size_t)(col + c) * SP + row)
            = make_float4(o[0][c], o[1][c], o[2][c], o[3][c]);
}

// ---------------- K2: bins + wv pair init (tag 0, all replicas) ----------------
__global__ __launch_bounds__(256) void k_init(float* __restrict__ E,
                                              float* __restrict__ F,
                                              u64* __restrict__ wvb0,
                                              const float* __restrict__ alpha) {
    const int t = blockIdx.x * 256 + threadIdx.x;
    const float ea = expf(alpha[0]);
    if (t < NINNER) {
        E[(size_t)t * SP + NINNER] = ea;        // E bin column (epilogue only)
        F[(size_t)t * SP + NINNER] = ea;        // F bin column
        const u64 p0 = make_pair(1.0f, 0u);     // v0 = 0 -> wv = 1, tag 0
#pragma unroll
        for (int r = 0; r < RREP; ++r)
            wvb0[r * PSTRIDE + t] = p0;
    }
    if (t <= NINNER) {
        E[(size_t)NINNER * SP + t] = ea;        // E bin row (+corner)
        F[(size_t)NINNER * SP + t] = ea;        // F bin row (+corner)
    }
}

// ---------------- masked hot poll + light backoff ----------------
__device__ __forceinline__ void poll8(const u64* buf, int tid, unsigned want, float* w) {
    u64 a[8];
#pragma unroll
    for (int q = 0; q < 8; ++q)
        a[q] = __hip_atomic_load(buf + q * 256 + tid, __ATOMIC_RELAXED, __HIP_MEMORY_SCOPE_AGENT);
    for (;;) {
        unsigned miss = 0u;
#pragma unroll
        for (int q = 0; q < 8; ++q)
            miss |= (pair_tag(a[q]) != want) ? (1u << q) : 0u;
        if (!miss) break;
        __builtin_amdgcn_s_sleep(2);     // ~128 cyc backoff: cut poll-storm contention
#pragma unroll
        for (int q = 0; q < 8; ++q)
            if (miss & (1u << q))
                a[q] = __hip_atomic_load(buf + q * 256 + tid, __ATOMIC_RELAXED, __HIP_MEMORY_SCOPE_AGENT);
    }
#pragma unroll
    for (int q = 0; q < 8; ++q) w[q] = pair_val(a[q]);
}

// ---------------- K3: persistent Sinkhorn — replicated tagged dataflow ----------------
// r7 structure: block b owns rows [8b,8b+8) of E and cols [8b,8b+8) of F in
// registers; wu/wv exchanged as (tag,value) u64 atoms, parity double-buffered.
// NEW: RREP=4 replicas. Producers store to all replicas; consumer block b polls
// only replica b&3 -> 64 readers/line instead of 256, so the publish store
// queues behind a 4x shallower read storm at its MALL slice. Dustbin
// potentials locally replicated (r6). Causal chain bounds parity skew < 2
// iters per replica (no overwrite-before-read); 0xAA poison never matches a
// wanted tag (0..100).
__global__ __launch_bounds__(256, 1) void k_sinkhorn(const float* __restrict__ E,
                                                     const float* __restrict__ F,
                                                     u64* wub, u64* wvb,
                                                     const float* __restrict__ alpha) {
    const int b = blockIdx.x, tid = threadIdx.x;
    const int lane = tid & 63, wid = tid >> 6;
    const int base = b * 8;
    const int rep = b & (RREP - 1);
    const bool lastb = (b == NB - 1);
    __shared__ float red[2][4][9];

    const float norm = -8.317766166719343f;            // -log(4096)
    const float logbin = 7.624618986159398f + norm;     // log(2048) + norm
    const float ea = expf(alpha[0]);

    // register-resident fragments: eR[r][q] = E[base+r][q*256+tid]
    float eR[8][8], fR[8][8];
#pragma unroll
    for (int r = 0; r < 8; ++r) {
        const float* rowE = E + (size_t)(base + r) * SP;
        const float* rowF = F + (size_t)(base + r) * SP;
#pragma unroll
        for (int q = 0; q < 8; ++q) {
            eR[r][q] = rowE[q * 256 + tid];
            fR[r][q] = rowF[q * 256 + tid];
        }
    }

    float u = 0.0f, v = 0.0f;              // potentials for row/col base+tid (tid<8)
    float ub = 0.0f, vb = 0.0f;            // dustbin potentials — local replicas
    float eub = 1.0f, evb = 1.0f;

    for (int it = 0; it < ITERS_N; ++it) {
        // ---- phase A: consume wv tag it, produce wu tag it+1 ----
        {
            const u64* src = wvb + ((size_t)(it & 1) * RREP + rep) * PSTRIDE;
            u64* dst = wub + (size_t)((it + 1) & 1) * RREP * PSTRIDE;
            const unsigned prod = (unsigned)(it + 1);
            float w[8];
            poll8(src, tid, (unsigned)it, w);
            float p[8];
#pragma unroll
            for (int r = 0; r < 8; ++r) {
                float s = 0.0f;
#pragma unroll
                for (int q = 0; q < 8; ++q) s = fmaf(eR[r][q], w[q], s);
                p[r] = s;
            }
            float t = w[0] + w[1] + w[2] + w[3] + w[4] + w[5] + w[6] + w[7];
#pragma unroll
            for (int r = 0; r < 8; ++r) {
                float s = p[r];
#pragma unroll
                for (int m = 1; m < 64; m <<= 1) s += __shfl_xor(s, m, 64);
                if (lane == 0) red[0][wid][r] = s;
            }
#pragma unroll
            for (int m = 1; m < 64; m <<= 1) t += __shfl_xor(t, m, 64);
            if (lane == 0) red[0][wid][8] = t;
            __syncthreads();
            if (tid < 8) {
                const float S = red[0][0][tid] + red[0][1][tid] + red[0][2][tid] + red[0][3][tid]
                              + ea * evb;
                const float unew = (norm - logf(S)) / TAU_F;
                u = u + EPS_F * (unew - u);
                const u64 pkt = make_pair(expf(u), prod);
#pragma unroll
                for (int rr = 0; rr < RREP; ++rr)
                    __hip_atomic_store(dst + rr * PSTRIDE + base + tid, pkt,
                                       __ATOMIC_RELAXED, __HIP_MEMORY_SCOPE_AGENT);
            }
            // local dustbin update (all threads, identical result)
            const float tsum = red[0][0][8] + red[0][1][8] + red[0][2][8] + red[0][3][8];
            const float Sbin = ea * (tsum + evb);
            ub = ub + EPS_F * ((logbin - logf(Sbin)) / TAU_F - ub);
            eub = expf(ub);
        }
        // ---- phase B: consume wu tag it+1, produce wv tag it+1 ----
        {
            const u64* src = wub + ((size_t)((it + 1) & 1) * RREP + rep) * PSTRIDE;
            u64* dst = wvb + (size_t)((it + 1) & 1) * RREP * PSTRIDE;
            const unsigned prod = (unsigned)(it + 1);
            float w[8];
            poll8(src, tid, prod, w);
            float p[8];
#pragma unroll
            for (int r = 0; r < 8; ++r) {
                float s = 0.0f;
#pragma unroll
                for (int q = 0; q < 8; ++q) s = fmaf(fR[r][q], w[q], s);
                p[r] = s;
            }
            float t = w[0] + w[1] + w[2] + w[3] + w[4] + w[5] + w[6] + w[7];
#pragma unroll
            for (int r = 0; r < 8; ++r) {
                float s = p[r];
#pragma unroll
                for (int m = 1; m < 64; m <<= 1) s += __shfl_xor(s, m, 64);
                if (lane == 0) red[1][wid][r] = s;
            }
#pragma unroll
            for (int m = 1; m < 64; m <<= 1) t += __shfl_xor(t, m, 64);
            if (lane == 0) red[1][wid][8] = t;
            __syncthreads();
            if (tid < 8) {
                const float T = red[1][0][tid] + red[1][1][tid] + red[1][2][tid] + red[1][3][tid]
                              + ea * eub;
                const float vnew = (norm - logf(T)) / TAU_F;
                v = v + EPS_F * (vnew - v);
                const u64 pkt = make_pair(expf(v), prod);
#pragma unroll
                for (int rr = 0; rr < RREP; ++rr)
                    __hip_atomic_store(dst + rr * PSTRIDE + base + tid, pkt,
                                       __ATOMIC_RELAXED, __HIP_MEMORY_SCOPE_AGENT);
            }
            const float tsum = red[1][0][8] + red[1][1][8] + red[1][2][8] + red[1][3][8];
            const float Tbin = ea * (tsum + eub);
            vb = vb + EPS_F * ((logbin - logf(Tbin)) / TAU_F - vb);
            evb = expf(vb);
        }
    }
    // publish final dustbin scalings (tag 100 -> parity 0, replica 0) for epilogue
    if (lastb && tid == 0) {
        __hip_atomic_store(wub + NINNER, make_pair(eub, (unsigned)ITERS_N),
                           __ATOMIC_RELAXED, __HIP_MEMORY_SCOPE_AGENT);
        __hip_atomic_store(wvb + NINNER, make_pair(evb, (unsigned)ITERS_N),
                           __ATOMIC_RELAXED, __HIP_MEMORY_SCOPE_AGENT);
    }
}

// ---------------- K4: fused epilogue — out0 = exp(Z), row argmax, col argmax ----------
// final wu/wv: tag 100 (even) -> parity-0 replica-0 halves -> .x of float2 pairs
__global__ __launch_bounds__(256) void k_finish(const float* __restrict__ E,
                                                const float* __restrict__ F,
                                                const float2* __restrict__ wup,
                                                const float2* __restrict__ wvp,
                                                float* __restrict__ out,
                                                float* __restrict__ max0,
                                                int* __restrict__ idx0,
                                                int* __restrict__ idx1) {
    const int i = blockIdx.x;                 // 0..2048
    const int tid = threadIdx.x;
    const int lane = tid & 63, wid = tid >> 6;
    __shared__ float sb[4]; __shared__ int si[4];

    // --- row part: write out row i, argmax over inner cols ---
    {
        const float wui = wup[i].x * 4096.0f;     // * exp(-norm)
        const float* row = E + (size_t)i * SP;
        float best = -1.0f; int bidx = 0;
        for (int j = tid; j < NROW; j += 256) {
            const float val = row[j] * wvp[j].x * wui;
            out[(size_t)i * NROW + j] = val;
            if (j < NINNER && val > best) { best = val; bidx = j; }
        }
        if (i < NINNER) {
#pragma unroll
            for (int m = 1; m < 64; m <<= 1) {
                const float ob = __shfl_xor(best, m, 64);
                const int   oi = __shfl_xor(bidx, m, 64);
                if (ob > best || (ob == best && oi < bidx)) { best = ob; bidx = oi; }
            }
            if (lane == 0) { sb[wid] = best; si[wid] = bidx; }
            __syncthreads();
            if (tid == 0) {
                for (int k = 1; k < 4; ++k)
                    if (sb[k] > best || (sb[k] == best && si[k] < bidx)) { best = sb[k]; bidx = si[k]; }
                max0[i] = best; idx0[i] = bidx;
            }
        }
    }

    // --- col part: argmax of column i over inner rows (via F) ---
    if (i < NINNER) {
        __syncthreads();                          // sb/si reuse safety
        const float* row = F + (size_t)i * SP;
        float best = -1.0f; int bidx = 0;
        for (int r = tid; r < NINNER; r += 256) {
            const float q = row[r] * wup[r].x;
            if (q > best) { best = q; bidx = r; }
        }
#pragma unroll
        for (int m = 1; m < 64; m <<= 1) {
            const float ob = __shfl_xor(best, m, 64);
            const int   oi = __shfl_xor(bidx, m, 64);
            if (ob > best || (ob == best && oi < bidx)) { best = ob; bidx = oi; }
        }
        if (lane == 0) { sb[wid] = best; si[wid] = bidx; }
        __syncthreads();
        if (tid == 0) {
            for (int k = 1; k < 4; ++k)
                if (sb[k] > best || (sb[k] == best && si[k] < bidx)) { best = sb[k]; bidx = si[k]; }
            idx1[i] = bidx;
        }
    }
}

// ---------------- K5a/K5b: mutual matching ----------------
__global__ __launch_bounds__(256) void k_match0(const float* __restrict__ max0,
                                                const int* __restrict__ idx0,
                                                const int* __restrict__ idx1,
                                                float* __restrict__ ms0,
                                                int* __restrict__ vld0,
                                                float* __restrict__ out) {
    const int i = blockIdx.x * 256 + threadIdx.x;
    if (i >= NINNER) return;
    const int j = idx0[i];
    const bool mut = (idx1[j] == i);
    const float ms = mut ? max0[i] : 0.0f;
    const bool val = mut && (ms > 0.2f);
    ms0[i] = ms; vld0[i] = val ? 1 : 0;
    out[OOFF_I0 + i] = val ? (float)j : -1.0f;
    out[OOFF_S0 + i] = ms;
}
__global__ __launch_bounds__(256) void k_match1(const int* __restrict__ idx0,
                                                const int* __restrict__ idx1,
                                                const float* __restrict__ ms0,
                                                const int* __restrict__ vld0,
                                                float* __restrict__ out) {
    const int j = blockIdx.x * 256 + threadIdx.x;
    if (j >= NINNER) return;
    const int i = idx1[j];
    const bool mut = (idx0[i] == j);
    const float ms = mut ? ms0[i] : 0.0f;
    const bool val = mut && (vld0[i] != 0);
    out[OOFF_I1 + j] = val ? (float)i : -1.0f;
    out[OOFF_S1 + j] = ms;
}

// ---------------- host ----------------
extern "C" void kernel_launch(void* const* d_in, const int* in_sizes, int n_in,
                              void* d_out, int out_size, void* d_ws, size_t ws_size,
                              hipStream_t stream) {
    const float* A     = (const float*)d_in[0];   // mdesc0 (1,256,2048)
    const float* Bm    = (const float*)d_in[1];   // mdesc1 (1,256,2048)
    const float* alpha = (const float*)d_in[2];   // bin_score scalar

    float* ws = (float*)d_ws;
    float* E    = ws + OFF_E;
    float* F    = ws + OFF_F;
    u64*   wub  = (u64*)(ws + OFF_WUP);
    u64*   wvb  = (u64*)(ws + OFF_WVP);
    float* max0 = ws + OFF_MAX0;
    int*   idx0 = (int*)(ws + OFF_IDX0);
    int*   idx1 = (int*)(ws + OFF_IDX1);
    float* ms0  = ws + OFF_MS0;
    int*   vld0 = (int*)(ws + OFF_VLD0);
    float* out  = (float*)d_out;

    k_gemm<<<dim3(32, 32), 256, 0, stream>>>(A, Bm, E, F);
    k_init<<<dim3(9), 256, 0, stream>>>(E, F, wvb, alpha);
    k_sinkhorn<<<dim3(NB), NT, 0, stream>>>(E, F, wub, wvb, alpha);
    // final tag 100 (even) -> parity-0 replica-0 halves of both pair buffers
    k_finish<<<dim3(NROW), 256, 0, stream>>>(E, F, (const float2*)wub, (const float2*)wvb,
                                             out, max0, idx0, idx1);
    k_match0<<<dim3(8), 256, 0, stream>>>(max0, idx0, idx1, ms0, vld0, out);
    k_match1<<<dim3(8), 256, 0, stream>>>(idx0, idx1, ms0, vld0, out);
}